// Round 1
// baseline (150.762 us; speedup 1.0000x reference)
//
#include <hip/hip_runtime.h>

// BinaryLinear: out[8192][2048] = x[8192][2048] @ (w[2048][2048] > 0)
// Strategy: bf16 MFMA GEMM, fused on-the-fly conversion (x -> bf16 RNE,
// w -> {0,1} bf16 exact). Reg-staged 128x128 tile, BK=32, 4 waves (2x2),
// each wave 64x64 = 4x4 frags of mfma_f32_16x16x32_bf16.

#define MDIM 8192
#define NDIM 2048
#define KDIM 2048
#define BM 128
#define BN 128
#define BK 32

typedef __attribute__((ext_vector_type(8))) short short8;
typedef __attribute__((ext_vector_type(4))) float float4v;
typedef __attribute__((ext_vector_type(4))) unsigned short ushort4v;

__device__ __forceinline__ unsigned short f2bf(float f) {
    union { float f; unsigned u; } v; v.f = f;
    unsigned r = v.u + 0x7FFFu + ((v.u >> 16) & 1u);
    return (unsigned short)(r >> 16);
}

__global__ __launch_bounds__(256, 2) void binlin_gemm(
        const float* __restrict__ X, const float* __restrict__ W,
        float* __restrict__ O) {
    const int tid  = threadIdx.x;
    const int lane = tid & 63;
    const int wave = tid >> 6;
    const int wr = wave >> 1;          // wave row 0..1
    const int wc = wave & 1;           // wave col 0..1

    // bijective XCD swizzle (nwg = 1024, 1024 % 8 == 0)
    const int NWG = (MDIM / BM) * (NDIM / BN);   // 64 * 16 = 1024
    int id  = blockIdx.x;
    int swz = (id & 7) * (NWG >> 3) + (id >> 3);
    const int bm = swz >> 4;           // / (NDIM/BN) = /16
    const int bn = swz & 15;

    // LDS: [row][k] bf16, padded to 40 shorts (80 B) per row -> 16B-aligned frags
    __shared__ __align__(16) unsigned short As[BM][40];
    __shared__ __align__(16) unsigned short Bs[BN][40];   // Bs[n][k] = Wbin[k][n]

    // ---- global load indexing ----
    // A: thread t loads 4x float4: rows rA + 32*p, k = kA..kA+3
    const int rA = tid >> 3;              // 0..31
    const int kA = (tid & 7) * 4;         // 0..28
    const float* aPtr = X + (size_t)(bm * BM + rA) * KDIM + kA;
    // B: thread t loads 4x float4: k rows kB+dk, n = nB..nB+3
    const int nB = (tid & 31) * 4;        // 0..124
    const int kB = (tid >> 5) * 4;        // 0..28
    const float* bPtr = W + (size_t)kB * NDIM + (size_t)bn * BN + nB;

    float4v aReg[4];
    float4v bReg[4];

    // prologue: load tile kt=0
#pragma unroll
    for (int p = 0; p < 4; ++p)
        aReg[p] = *reinterpret_cast<const float4v*>(aPtr + (size_t)(32 * p) * KDIM);
#pragma unroll
    for (int dk = 0; dk < 4; ++dk)
        bReg[dk] = *reinterpret_cast<const float4v*>(bPtr + (size_t)dk * NDIM);

    float4v acc[4][4];
#pragma unroll
    for (int i = 0; i < 4; ++i)
#pragma unroll
        for (int j = 0; j < 4; ++j) {
            acc[i][j].x = 0.f; acc[i][j].y = 0.f; acc[i][j].z = 0.f; acc[i][j].w = 0.f;
        }

    const int r16 = lane & 15;
    const int g8  = (lane >> 4) * 8;

    for (int kt = 0; kt < KDIM; kt += BK) {
        // ---- stage A: f32 -> bf16 (RNE), write [row][k] ----
#pragma unroll
        for (int p = 0; p < 4; ++p) {
            ushort4v v;
            v.x = f2bf(aReg[p].x); v.y = f2bf(aReg[p].y);
            v.z = f2bf(aReg[p].z); v.w = f2bf(aReg[p].w);
            *reinterpret_cast<ushort4v*>(&As[rA + 32 * p][kA]) = v;
        }
        // ---- stage B: binarize + transpose, write Bs[n][k] ----
        unsigned short bb[4][4];
#pragma unroll
        for (int dk = 0; dk < 4; ++dk) {
#pragma unroll
            for (int dn = 0; dn < 4; ++dn)
                bb[dn][dk] = (bReg[dk][dn] > 0.0f) ? (unsigned short)0x3F80u
                                                   : (unsigned short)0u;
        }
#pragma unroll
        for (int dn = 0; dn < 4; ++dn) {
            ushort4v v;
            v.x = bb[dn][0]; v.y = bb[dn][1]; v.z = bb[dn][2]; v.w = bb[dn][3];
            *reinterpret_cast<ushort4v*>(&Bs[nB + dn][kB]) = v;
        }
        __syncthreads();

        // ---- prefetch next tile into regs (overlaps with MFMA below) ----
        if (kt + BK < KDIM) {
#pragma unroll
            for (int p = 0; p < 4; ++p)
                aReg[p] = *reinterpret_cast<const float4v*>(
                    aPtr + (size_t)(32 * p) * KDIM + (kt + BK));
#pragma unroll
            for (int dk = 0; dk < 4; ++dk)
                bReg[dk] = *reinterpret_cast<const float4v*>(
                    bPtr + (size_t)(kt + BK + dk) * NDIM);
        }

        // ---- fragments + MFMA ----
        short8 af[4], bf[4];
#pragma unroll
        for (int mi = 0; mi < 4; ++mi)
            af[mi] = *reinterpret_cast<const short8*>(&As[wr * 64 + mi * 16 + r16][g8]);
#pragma unroll
        for (int ni = 0; ni < 4; ++ni)
            bf[ni] = *reinterpret_cast<const short8*>(&Bs[wc * 64 + ni * 16 + r16][g8]);
#pragma unroll
        for (int mi = 0; mi < 4; ++mi)
#pragma unroll
            for (int ni = 0; ni < 4; ++ni)
                acc[mi][ni] = __builtin_amdgcn_mfma_f32_16x16x32_bf16(
                    af[mi], bf[ni], acc[mi][ni], 0, 0, 0);

        __syncthreads();
    }

    // ---- epilogue: C/D layout col = lane&15, row = 4*(lane>>4) + reg ----
    const int orow0 = bm * BM + wr * 64 + (lane >> 4) * 4;
    const int ocol0 = bn * BN + wc * 64 + (lane & 15);
#pragma unroll
    for (int mi = 0; mi < 4; ++mi)
#pragma unroll
        for (int ni = 0; ni < 4; ++ni)
#pragma unroll
            for (int r = 0; r < 4; ++r)
                O[(size_t)(orow0 + mi * 16 + r) * NDIM + ocol0 + ni * 16] =
                    acc[mi][ni][r];
}

extern "C" void kernel_launch(void* const* d_in, const int* in_sizes, int n_in,
                              void* d_out, int out_size, void* d_ws, size_t ws_size,
                              hipStream_t stream) {
    const float* X = (const float*)d_in[0];
    const float* W = (const float*)d_in[1];
    float* O = (float*)d_out;
    (void)in_sizes; (void)n_in; (void)out_size; (void)d_ws; (void)ws_size;

    dim3 grid((MDIM / BM) * (NDIM / BN));   // 1024
    dim3 block(256);
    binlin_gemm<<<grid, block, 0, stream>>>(X, W, O);
}

// Round 2
// 121.982 us; speedup vs baseline: 1.2359x; 1.2359x over previous
//
#include <hip/hip_runtime.h>

// BinaryLinear two-pass:
//   pass 1a: X f32 -> bf16 (RNE) into ws
//   pass 1b: W f32 (KxN) -> binarized bf16 {0,1}, TRANSPOSED to NxK into ws
//   pass 2 : bf16 GEMM C = Xb (MxK) . WtT (NxK row-major, i.e. B^T input),
//            m97 structure: 128x128 tile, BK=32, global_load_lds width 16.
// Fallback: if ws_size too small, run the round-1 fused kernel.

#define MDIM 8192
#define NDIM 2048
#define KDIM 2048

typedef __attribute__((ext_vector_type(8))) short short8;
typedef __attribute__((ext_vector_type(4))) float float4v;
typedef __attribute__((ext_vector_type(4))) float f32x4;
typedef __attribute__((ext_vector_type(4))) unsigned short ushort4v;
typedef __attribute__((ext_vector_type(8))) unsigned short ushort8v;

__device__ __forceinline__ unsigned short f2bf(float f) {
    union { float f; unsigned u; } v; v.f = f;
    unsigned r = v.u + 0x7FFFu + ((v.u >> 16) & 1u);
    return (unsigned short)(r >> 16);
}

__device__ __forceinline__ void gload_lds16(void* lds, const void* g) {
    __builtin_amdgcn_global_load_lds(
        (const __attribute__((address_space(1))) unsigned int*)g,
        (__attribute__((address_space(3))) unsigned int*)lds,
        16, 0, 0);
}

// ---------------- pass 1a: X -> bf16 ----------------
__global__ __launch_bounds__(256) void cvt_x(const float* __restrict__ X,
                                             unsigned short* __restrict__ Xb) {
    size_t i = ((size_t)blockIdx.x * 256 + threadIdx.x) * 8;
    float4v a = *reinterpret_cast<const float4v*>(X + i);
    float4v b = *reinterpret_cast<const float4v*>(X + i + 4);
    ushort8v o;
    o[0] = f2bf(a[0]); o[1] = f2bf(a[1]); o[2] = f2bf(a[2]); o[3] = f2bf(a[3]);
    o[4] = f2bf(b[0]); o[5] = f2bf(b[1]); o[6] = f2bf(b[2]); o[7] = f2bf(b[3]);
    *reinterpret_cast<ushort8v*>(Xb + i) = o;
}

// ---------------- pass 1b: binarize + transpose W ----------------
__global__ __launch_bounds__(256) void bin_w(const float* __restrict__ W,
                                             unsigned short* __restrict__ Wt) {
    __shared__ __align__(16) unsigned short T[64][72];   // pad 72 -> 144B rows, 16B-aligned
    const int t = threadIdx.x;
    const int k0 = (blockIdx.x >> 5) * 64;
    const int n0 = (blockIdx.x & 31) * 64;
    const int kr = t >> 4;              // 0..15
    const int nc = (t & 15) * 4;        // 0..60
#pragma unroll
    for (int rr = 0; rr < 4; ++rr) {
        int k = k0 + rr * 16 + kr;
        float4v w4 = *reinterpret_cast<const float4v*>(W + (size_t)k * NDIM + n0 + nc);
#pragma unroll
        for (int c = 0; c < 4; ++c)
            T[nc + c][rr * 16 + kr] = (w4[c] > 0.0f) ? (unsigned short)0x3F80u
                                                     : (unsigned short)0u;
    }
    __syncthreads();
    const int nl = t >> 2, ch = t & 3;
    ushort8v v0 = *reinterpret_cast<const ushort8v*>(&T[nl][ch * 16]);
    ushort8v v1 = *reinterpret_cast<const ushort8v*>(&T[nl][ch * 16 + 8]);
    unsigned short* dst = Wt + (size_t)(n0 + nl) * KDIM + k0 + ch * 16;
    *reinterpret_cast<ushort8v*>(dst) = v0;
    *reinterpret_cast<ushort8v*>(dst + 8) = v1;
}

// ---------------- pass 2: bf16 GEMM, B^T input (m97 structure) ----------------
__global__ __launch_bounds__(256) void gemm_bt(const unsigned short* __restrict__ A,
                                               const unsigned short* __restrict__ Bt,
                                               float* __restrict__ O) {
    __shared__ __align__(16) unsigned short As[128 * 32];
    __shared__ __align__(16) unsigned short Bs[128 * 32];
    const int tid = threadIdx.x;
    const int lane = tid & 63;
    const int w = tid >> 6;
    const int wr = w >> 1, wc = w & 1;

    const int NWG = (MDIM / 128) * (NDIM / 128);       // 1024, %8==0 -> bijective
    int id = blockIdx.x;
    int swz = (id & 7) * (NWG >> 3) + (id >> 3);
    const int bm = swz >> 4;
    const int bn = swz & 15;

    // global src (bytes): row = w*32 + (lane>>2) (+16 for j=1), inner = (lane&3)*16
    const int row_a = w * 32 + (lane >> 2);
    const char* gA = (const char*)A + ((size_t)(bm * 128 + row_a) * KDIM) * 2 + (lane & 3) * 16;
    const char* gB = (const char*)Bt + ((size_t)(bn * 128 + row_a) * KDIM) * 2 + (lane & 3) * 16;
    // wave-uniform LDS dest bases (HW adds lane*16)
    char* lA = (char*)As + w * 2048;
    char* lB = (char*)Bs + w * 2048;

    f32x4 acc[4][4];
#pragma unroll
    for (int i = 0; i < 4; ++i)
#pragma unroll
        for (int j = 0; j < 4; ++j) {
            acc[i][j][0] = 0.f; acc[i][j][1] = 0.f; acc[i][j][2] = 0.f; acc[i][j][3] = 0.f;
        }

    const int r16 = lane & 15;
    const int g8 = (lane >> 4) * 8;
    int aoff[4], boff[4];
#pragma unroll
    for (int mi = 0; mi < 4; ++mi) aoff[mi] = (wr * 64 + mi * 16 + r16) * 32 + g8;
#pragma unroll
    for (int ni = 0; ni < 4; ++ni) boff[ni] = (wc * 64 + ni * 16 + r16) * 32 + g8;

    for (int kt = 0; kt < KDIM; kt += 32) {
        __syncthreads();                       // LDS free (prev reads done)
        gload_lds16(lA, gA);
        gload_lds16(lA + 1024, gA + (size_t)16 * KDIM * 2);
        gload_lds16(lB, gB);
        gload_lds16(lB + 1024, gB + (size_t)16 * KDIM * 2);
        gA += 64; gB += 64;                    // advance 32 bf16 in k
        __syncthreads();                       // vmcnt(0) drain -> tile ready

        short8 af[4], bf[4];
#pragma unroll
        for (int mi = 0; mi < 4; ++mi)
            af[mi] = *reinterpret_cast<const short8*>(As + aoff[mi]);
#pragma unroll
        for (int ni = 0; ni < 4; ++ni)
            bf[ni] = *reinterpret_cast<const short8*>(Bs + boff[ni]);
#pragma unroll
        for (int mi = 0; mi < 4; ++mi)
#pragma unroll
            for (int ni = 0; ni < 4; ++ni)
                acc[mi][ni] = __builtin_amdgcn_mfma_f32_16x16x32_bf16(
                    af[mi], bf[ni], acc[mi][ni], 0, 0, 0);
    }

    const int orow0 = bm * 128 + wr * 64 + (lane >> 4) * 4;
    const int ocol0 = bn * 128 + wc * 64 + r16;
#pragma unroll
    for (int mi = 0; mi < 4; ++mi)
#pragma unroll
        for (int ni = 0; ni < 4; ++ni)
#pragma unroll
            for (int r = 0; r < 4; ++r)
                O[(size_t)(orow0 + mi * 16 + r) * NDIM + ocol0 + ni * 16] =
                    acc[mi][ni][r];
}

// ---------------- round-1 fused kernel (fallback if ws too small) ----------------
__global__ __launch_bounds__(256, 2) void binlin_fused(
        const float* __restrict__ X, const float* __restrict__ W,
        float* __restrict__ O) {
    const int tid = threadIdx.x;
    const int lane = tid & 63;
    const int wave = tid >> 6;
    const int wr = wave >> 1, wc = wave & 1;
    const int NWG = (MDIM / 128) * (NDIM / 128);
    int id = blockIdx.x;
    int swz = (id & 7) * (NWG >> 3) + (id >> 3);
    const int bm = swz >> 4, bn = swz & 15;

    __shared__ __align__(16) unsigned short As[128][40];
    __shared__ __align__(16) unsigned short Bs[128][40];

    const int rA = tid >> 3, kA = (tid & 7) * 4;
    const float* aPtr = X + (size_t)(bm * 128 + rA) * KDIM + kA;
    const int nB = (tid & 31) * 4, kB = (tid >> 5) * 4;
    const float* bPtr = W + (size_t)kB * NDIM + (size_t)bn * 128 + nB;

    float4v aReg[4], bReg[4];
#pragma unroll
    for (int p = 0; p < 4; ++p)
        aReg[p] = *reinterpret_cast<const float4v*>(aPtr + (size_t)(32 * p) * KDIM);
#pragma unroll
    for (int dk = 0; dk < 4; ++dk)
        bReg[dk] = *reinterpret_cast<const float4v*>(bPtr + (size_t)dk * NDIM);

    f32x4 acc[4][4];
#pragma unroll
    for (int i = 0; i < 4; ++i)
#pragma unroll
        for (int j = 0; j < 4; ++j) {
            acc[i][j][0] = 0.f; acc[i][j][1] = 0.f; acc[i][j][2] = 0.f; acc[i][j][3] = 0.f;
        }

    const int r16 = lane & 15, g8 = (lane >> 4) * 8;
    for (int kt = 0; kt < KDIM; kt += 32) {
#pragma unroll
        for (int p = 0; p < 4; ++p) {
            ushort4v v;
            v[0] = f2bf(aReg[p][0]); v[1] = f2bf(aReg[p][1]);
            v[2] = f2bf(aReg[p][2]); v[3] = f2bf(aReg[p][3]);
            *reinterpret_cast<ushort4v*>(&As[rA + 32 * p][kA]) = v;
        }
        unsigned short bb[4][4];
#pragma unroll
        for (int dk = 0; dk < 4; ++dk)
#pragma unroll
            for (int dn = 0; dn < 4; ++dn)
                bb[dn][dk] = (bReg[dk][dn] > 0.0f) ? (unsigned short)0x3F80u
                                                   : (unsigned short)0u;
#pragma unroll
        for (int dn = 0; dn < 4; ++dn) {
            ushort4v v;
            v[0] = bb[dn][0]; v[1] = bb[dn][1]; v[2] = bb[dn][2]; v[3] = bb[dn][3];
            *reinterpret_cast<ushort4v*>(&Bs[nB + dn][kB]) = v;
        }
        __syncthreads();
        if (kt + 32 < KDIM) {
#pragma unroll
            for (int p = 0; p < 4; ++p)
                aReg[p] = *reinterpret_cast<const float4v*>(
                    aPtr + (size_t)(32 * p) * KDIM + (kt + 32));
#pragma unroll
            for (int dk = 0; dk < 4; ++dk)
                bReg[dk] = *reinterpret_cast<const float4v*>(
                    bPtr + (size_t)(kt + 32 + dk) * NDIM);
        }
        short8 af[4], bf[4];
#pragma unroll
        for (int mi = 0; mi < 4; ++mi)
            af[mi] = *reinterpret_cast<const short8*>(&As[wr * 64 + mi * 16 + r16][g8]);
#pragma unroll
        for (int ni = 0; ni < 4; ++ni)
            bf[ni] = *reinterpret_cast<const short8*>(&Bs[wc * 64 + ni * 16 + r16][g8]);
#pragma unroll
        for (int mi = 0; mi < 4; ++mi)
#pragma unroll
            for (int ni = 0; ni < 4; ++ni)
                acc[mi][ni] = __builtin_amdgcn_mfma_f32_16x16x32_bf16(
                    af[mi], bf[ni], acc[mi][ni], 0, 0, 0);
        __syncthreads();
    }

    const int orow0 = bm * 128 + wr * 64 + (lane >> 4) * 4;
    const int ocol0 = bn * 128 + wc * 64 + r16;
#pragma unroll
    for (int mi = 0; mi < 4; ++mi)
#pragma unroll
        for (int ni = 0; ni < 4; ++ni)
#pragma unroll
            for (int r = 0; r < 4; ++r)
                O[(size_t)(orow0 + mi * 16 + r) * NDIM + ocol0 + ni * 16] =
                    acc[mi][ni][r];
}

extern "C" void kernel_launch(void* const* d_in, const int* in_sizes, int n_in,
                              void* d_out, int out_size, void* d_ws, size_t ws_size,
                              hipStream_t stream) {
    const float* X = (const float*)d_in[0];
    const float* W = (const float*)d_in[1];
    float* O = (float*)d_out;
    (void)in_sizes; (void)n_in; (void)out_size;

    const size_t xb_elems = (size_t)MDIM * KDIM;
    const size_t wt_elems = (size_t)NDIM * KDIM;
    const size_t need = (xb_elems + wt_elems) * sizeof(unsigned short);

    if (ws_size >= need) {
        unsigned short* Xb = (unsigned short*)d_ws;
        unsigned short* Wt = Xb + xb_elems;
        cvt_x<<<dim3(MDIM * KDIM / (256 * 8)), dim3(256), 0, stream>>>(X, Xb);
        bin_w<<<dim3((KDIM / 64) * (NDIM / 64)), dim3(256), 0, stream>>>(W, Wt);
        gemm_bt<<<dim3((MDIM / 128) * (NDIM / 128)), dim3(256), 0, stream>>>(Xb, Wt, O);
    } else {
        binlin_fused<<<dim3((MDIM / 128) * (NDIM / 128)), dim3(256), 0, stream>>>(X, W, O);
    }
}

// Round 3
// 84.326 us; speedup vs baseline: 1.7879x; 1.4466x over previous
//
#include <hip/hip_runtime.h>

// BinaryLinear three-kernel:
//   cvt_x : X f32 -> bf16 (RNE)
//   bin_w : W f32 (KxN) -> binarized bf16 {0,1}, transposed to NxK
//   gemm_8ph : 256x256 tile, BK=64, 8 waves, double-buffered 128KB LDS,
//              counted-vmcnt pipeline + XOR-swizzled LDS + setprio (T1..T5).
// Fallback: round-1 fused kernel if ws too small.

#define MDIM 8192
#define NDIM 2048
#define KDIM 2048
#define NT   (KDIM / 64)          // 32 K-tiles

typedef __attribute__((ext_vector_type(8))) short short8;
typedef __attribute__((ext_vector_type(4))) float float4v;
typedef __attribute__((ext_vector_type(4))) float f32x4;
typedef __attribute__((ext_vector_type(4))) unsigned short ushort4v;
typedef __attribute__((ext_vector_type(8))) unsigned short ushort8v;

__device__ __forceinline__ unsigned short f2bf(float f) {
    union { float f; unsigned u; } v; v.f = f;
    unsigned r = v.u + 0x7FFFu + ((v.u >> 16) & 1u);
    return (unsigned short)(r >> 16);
}

__device__ __forceinline__ void gload_lds16(void* l, const void* g) {
    __builtin_amdgcn_global_load_lds(
        (const __attribute__((address_space(1))) unsigned int*)g,
        (__attribute__((address_space(3))) unsigned int*)l,
        16, 0, 0);
}

// ---------------- pass 1a: X -> bf16 ----------------
__global__ __launch_bounds__(256) void cvt_x(const float* __restrict__ X,
                                             unsigned short* __restrict__ Xb) {
    size_t i = ((size_t)blockIdx.x * 256 + threadIdx.x) * 8;
    float4v a = *reinterpret_cast<const float4v*>(X + i);
    float4v b = *reinterpret_cast<const float4v*>(X + i + 4);
    ushort8v o;
    o[0] = f2bf(a[0]); o[1] = f2bf(a[1]); o[2] = f2bf(a[2]); o[3] = f2bf(a[3]);
    o[4] = f2bf(b[0]); o[5] = f2bf(b[1]); o[6] = f2bf(b[2]); o[7] = f2bf(b[3]);
    *reinterpret_cast<ushort8v*>(Xb + i) = o;
}

// ---------------- pass 1b: binarize + transpose W ----------------
__global__ __launch_bounds__(256) void bin_w(const float* __restrict__ W,
                                             unsigned short* __restrict__ Wt) {
    __shared__ __align__(16) unsigned short T[64][72];
    const int t = threadIdx.x;
    const int k0 = (blockIdx.x >> 5) * 64;
    const int n0 = (blockIdx.x & 31) * 64;
    const int kr = t >> 4;
    const int nc = (t & 15) * 4;
#pragma unroll
    for (int rr = 0; rr < 4; ++rr) {
        int k = k0 + rr * 16 + kr;
        float4v w4 = *reinterpret_cast<const float4v*>(W + (size_t)k * NDIM + n0 + nc);
#pragma unroll
        for (int c = 0; c < 4; ++c)
            T[nc + c][rr * 16 + kr] = (w4[c] > 0.0f) ? (unsigned short)0x3F80u
                                                     : (unsigned short)0u;
    }
    __syncthreads();
    const int nl = t >> 2, ch = t & 3;
    ushort8v v0 = *reinterpret_cast<const ushort8v*>(&T[nl][ch * 16]);
    ushort8v v1 = *reinterpret_cast<const ushort8v*>(&T[nl][ch * 16 + 8]);
    unsigned short* dst = Wt + (size_t)(n0 + nl) * KDIM + k0 + ch * 16;
    *reinterpret_cast<ushort8v*>(dst) = v0;
    *reinterpret_cast<ushort8v*>(dst + 8) = v1;
}

// ---------------- pass 2: 256x256 deep-pipelined bf16 GEMM ----------------
// LDS layout per buffer (65536 B): A tile [256 rows][64 k] at +0 (32 KB),
// B tile at +32768. Row stride 128 B. 16B slot s of row r stored at
// slot (s ^ (r&7))  [XOR swizzle; applied via pre-swizzled global source].
// Chunk j (8 KB) = rows [j*64, j*64+64) of A or B. Stage order per tile:
// ph0: B0,B1  ph1: B2,B3  ph2: A0,A2  ph3: A1,A3  (2 gload_lds each).
// Compute phase p uses A rows {wr*128 + 2p*16 ..+32} (chunks {0,2} for p<2,
// {1,3} for p>=2) + all B -> counted waits: ph0 vmcnt(2), ph2 vmcnt(4).
__global__ __launch_bounds__(512, 1) void gemm_8ph(const unsigned short* __restrict__ A,
                                                   const unsigned short* __restrict__ Bt,
                                                   float* __restrict__ O) {
    extern __shared__ char lds[];
    const int tid  = threadIdx.x;
    const int lane = tid & 63;
    const int w    = tid >> 6;       // 0..7
    const int wr   = w >> 2;         // 0..1
    const int wc   = w & 3;          // 0..3

    int id  = blockIdx.x;            // 256 blocks, 256 % 8 == 0 -> bijective
    int swz = (id & 7) * 32 + (id >> 3);
    const int bm = swz >> 3;         // 0..31
    const int bn = swz & 7;          // 0..7

    // ---- staging source: lane l fetches global slot (l&7)^(l>>3) of row w*8+(l>>3)
    const int l3 = lane >> 3, l7 = lane & 7;
    const int srcOff = (w * 8 + l3) * (KDIM * 2) + ((l7 ^ l3) << 4);
    const char* gA = (const char*)A + (size_t)(bm * 256) * (KDIM * 2) + srcOff;
    const char* gB = (const char*)Bt + (size_t)(bn * 256) * (KDIM * 2) + srcOff;
    // chunk j: +j*262144 global, +j*8192 LDS. K-tile t: +t*128 global.

    // ---- fragment read constants (swizzled) ----
    const int fr = lane & 15, fg = lane >> 4;
    const int se0 = ((fg)     ^ (fr & 7)) << 4;     // kk=0 slot byte offset
    const int se1 = ((4 + fg) ^ (fr & 7)) << 4;     // kk=1
    const int aRd = wr * 16384 + fr * 128;          // + buf + mi*2048 + se
    const int bRd = 32768 + wc * 8192 + fr * 128;   // + buf + ni*2048 + se

    f32x4 acc[8][4];
#pragma unroll
    for (int i = 0; i < 8; ++i)
#pragma unroll
        for (int j = 0; j < 4; ++j) {
            acc[i][j][0] = 0.f; acc[i][j][1] = 0.f;
            acc[i][j][2] = 0.f; acc[i][j][3] = 0.f;
        }

    // ---- prologue: stage tile 0 in steady-state order ----
    gload_lds16(lds + 32768 + 0 * 8192 + w * 1024, gB + 0 * 262144);
    gload_lds16(lds + 32768 + 1 * 8192 + w * 1024, gB + 1 * 262144);
    gload_lds16(lds + 32768 + 2 * 8192 + w * 1024, gB + 2 * 262144);
    gload_lds16(lds + 32768 + 3 * 8192 + w * 1024, gB + 3 * 262144);
    gload_lds16(lds + 0 * 8192 + w * 1024, gA + 0 * 262144);
    gload_lds16(lds + 2 * 8192 + w * 1024, gA + 2 * 262144);
    gload_lds16(lds + 1 * 8192 + w * 1024, gA + 1 * 262144);
    gload_lds16(lds + 3 * 8192 + w * 1024, gA + 3 * 262144);

    short8 bfr[4][2];

    for (int i = 0; i < NT; ++i) {
        const int cur = (i & 1) << 16;
        const int nxt = ((i + 1) & 1) << 16;
        const char* gAs = gA + (size_t)(i + 1) * 128;
        const char* gBs = gB + (size_t)(i + 1) * 128;
        const bool more = (i + 1 < NT);

#pragma unroll
        for (int p = 0; p < 4; ++p) {
            if (p == 0) {
                asm volatile("s_waitcnt vmcnt(2)" ::: "memory");
            } else if (p == 2) {
                if (i == NT - 1) asm volatile("s_waitcnt vmcnt(0)" ::: "memory");
                else             asm volatile("s_waitcnt vmcnt(4)" ::: "memory");
            }
            __builtin_amdgcn_s_barrier();
            asm volatile("" ::: "memory");

            // ---- ds reads for this phase ----
            short8 af[2][2];
#pragma unroll
            for (int d = 0; d < 2; ++d) {
                const int mi = 2 * p + d;
                af[d][0] = *reinterpret_cast<const short8*>(lds + cur + aRd + mi * 2048 + se0);
                af[d][1] = *reinterpret_cast<const short8*>(lds + cur + aRd + mi * 2048 + se1);
            }
            if (p == 0) {
#pragma unroll
                for (int ni = 0; ni < 4; ++ni) {
                    bfr[ni][0] = *reinterpret_cast<const short8*>(lds + cur + bRd + ni * 2048 + se0);
                    bfr[ni][1] = *reinterpret_cast<const short8*>(lds + cur + bRd + ni * 2048 + se1);
                }
            }

            // ---- stage 2 chunks of tile i+1 ----
            if (more) {
                if (p == 0) {
                    gload_lds16(lds + nxt + 32768 + 0 * 8192 + w * 1024, gBs + 0 * 262144);
                    gload_lds16(lds + nxt + 32768 + 1 * 8192 + w * 1024, gBs + 1 * 262144);
                } else if (p == 1) {
                    gload_lds16(lds + nxt + 32768 + 2 * 8192 + w * 1024, gBs + 2 * 262144);
                    gload_lds16(lds + nxt + 32768 + 3 * 8192 + w * 1024, gBs + 3 * 262144);
                } else if (p == 2) {
                    gload_lds16(lds + nxt + 0 * 8192 + w * 1024, gAs + 0 * 262144);
                    gload_lds16(lds + nxt + 2 * 8192 + w * 1024, gAs + 2 * 262144);
                } else {
                    gload_lds16(lds + nxt + 1 * 8192 + w * 1024, gAs + 1 * 262144);
                    gload_lds16(lds + nxt + 3 * 8192 + w * 1024, gAs + 3 * 262144);
                }
            }

            // ---- 16 MFMA ----
            __builtin_amdgcn_s_setprio(1);
#pragma unroll
            for (int d = 0; d < 2; ++d)
#pragma unroll
                for (int ni = 0; ni < 4; ++ni) {
                    acc[2 * p + d][ni] = __builtin_amdgcn_mfma_f32_16x16x32_bf16(
                        af[d][0], bfr[ni][0], acc[2 * p + d][ni], 0, 0, 0);
                    acc[2 * p + d][ni] = __builtin_amdgcn_mfma_f32_16x16x32_bf16(
                        af[d][1], bfr[ni][1], acc[2 * p + d][ni], 0, 0, 0);
                }
            __builtin_amdgcn_s_setprio(0);
        }
    }

    // ---- epilogue: C/D layout col = lane&15, row = 4*(lane>>4) + reg ----
    const int orow0 = bm * 256 + wr * 128 + fg * 4;
    const int ocol0 = bn * 256 + wc * 64 + fr;
#pragma unroll
    for (int mi = 0; mi < 8; ++mi)
#pragma unroll
        for (int r = 0; r < 4; ++r) {
            float* op = O + (size_t)(orow0 + mi * 16 + r) * NDIM + ocol0;
#pragma unroll
            for (int ni = 0; ni < 4; ++ni)
                op[ni * 16] = acc[mi][ni][r];
        }
}

// ---------------- fallback: round-1 fused kernel ----------------
__global__ __launch_bounds__(256, 2) void binlin_fused(
        const float* __restrict__ X, const float* __restrict__ W,
        float* __restrict__ O) {
    const int tid = threadIdx.x;
    const int lane = tid & 63;
    const int wave = tid >> 6;
    const int wr = wave >> 1, wc = wave & 1;
    const int NWG = (MDIM / 128) * (NDIM / 128);
    int id = blockIdx.x;
    int swz = (id & 7) * (NWG >> 3) + (id >> 3);
    const int bm = swz >> 4, bn = swz & 15;

    __shared__ __align__(16) unsigned short As[128][40];
    __shared__ __align__(16) unsigned short Bs[128][40];

    const int rA = tid >> 3, kA = (tid & 7) * 4;
    const float* aPtr = X + (size_t)(bm * 128 + rA) * KDIM + kA;
    const int nB = (tid & 31) * 4, kB = (tid >> 5) * 4;
    const float* bPtr = W + (size_t)kB * NDIM + (size_t)bn * 128 + nB;

    float4v aReg[4], bReg[4];
#pragma unroll
    for (int p = 0; p < 4; ++p)
        aReg[p] = *reinterpret_cast<const float4v*>(aPtr + (size_t)(32 * p) * KDIM);
#pragma unroll
    for (int dk = 0; dk < 4; ++dk)
        bReg[dk] = *reinterpret_cast<const float4v*>(bPtr + (size_t)dk * NDIM);

    f32x4 acc[4][4];
#pragma unroll
    for (int i = 0; i < 4; ++i)
#pragma unroll
        for (int j = 0; j < 4; ++j) {
            acc[i][j][0] = 0.f; acc[i][j][1] = 0.f; acc[i][j][2] = 0.f; acc[i][j][3] = 0.f;
        }

    const int r16 = lane & 15, g8 = (lane >> 4) * 8;
    for (int kt = 0; kt < KDIM; kt += 32) {
#pragma unroll
        for (int p = 0; p < 4; ++p) {
            ushort4v v;
            v[0] = f2bf(aReg[p][0]); v[1] = f2bf(aReg[p][1]);
            v[2] = f2bf(aReg[p][2]); v[3] = f2bf(aReg[p][3]);
            *reinterpret_cast<ushort4v*>(&As[rA + 32 * p][kA]) = v;
        }
        unsigned short bb[4][4];
#pragma unroll
        for (int dk = 0; dk < 4; ++dk)
#pragma unroll
            for (int dn = 0; dn < 4; ++dn)
                bb[dn][dk] = (bReg[dk][dn] > 0.0f) ? (unsigned short)0x3F80u
                                                   : (unsigned short)0u;
#pragma unroll
        for (int dn = 0; dn < 4; ++dn) {
            ushort4v v;
            v[0] = bb[dn][0]; v[1] = bb[dn][1]; v[2] = bb[dn][2]; v[3] = bb[dn][3];
            *reinterpret_cast<ushort4v*>(&Bs[nB + dn][kB]) = v;
        }
        __syncthreads();
        if (kt + 32 < KDIM) {
#pragma unroll
            for (int p = 0; p < 4; ++p)
                aReg[p] = *reinterpret_cast<const float4v*>(
                    aPtr + (size_t)(32 * p) * KDIM + (kt + 32));
#pragma unroll
            for (int dk = 0; dk < 4; ++dk)
                bReg[dk] = *reinterpret_cast<const float4v*>(
                    bPtr + (size_t)(kt + 32 + dk) * NDIM);
        }
        short8 af[4], bf[4];
#pragma unroll
        for (int mi = 0; mi < 4; ++mi)
            af[mi] = *reinterpret_cast<const short8*>(&As[wr * 64 + mi * 16 + r16][g8]);
#pragma unroll
        for (int ni = 0; ni < 4; ++ni)
            bf[ni] = *reinterpret_cast<const short8*>(&Bs[wc * 64 + ni * 16 + r16][g8]);
#pragma unroll
        for (int mi = 0; mi < 4; ++mi)
#pragma unroll
            for (int ni = 0; ni < 4; ++ni)
                acc[mi][ni] = __builtin_amdgcn_mfma_f32_16x16x32_bf16(
                    af[mi], bf[ni], acc[mi][ni], 0, 0, 0);
        __syncthreads();
    }

    const int orow0 = bm * 128 + wr * 64 + (lane >> 4) * 4;
    const int ocol0 = bn * 128 + wc * 64 + r16;
#pragma unroll
    for (int mi = 0; mi < 4; ++mi)
#pragma unroll
        for (int ni = 0; ni < 4; ++ni)
#pragma unroll
            for (int r = 0; r < 4; ++r)
                O[(size_t)(orow0 + mi * 16 + r) * NDIM + ocol0 + ni * 16] =
                    acc[mi][ni][r];
}

extern "C" void kernel_launch(void* const* d_in, const int* in_sizes, int n_in,
                              void* d_out, int out_size, void* d_ws, size_t ws_size,
                              hipStream_t stream) {
    const float* X = (const float*)d_in[0];
    const float* W = (const float*)d_in[1];
    float* O = (float*)d_out;
    (void)in_sizes; (void)n_in; (void)out_size;

    const size_t xb_elems = (size_t)MDIM * KDIM;
    const size_t wt_elems = (size_t)NDIM * KDIM;
    const size_t need = (xb_elems + wt_elems) * sizeof(unsigned short);

    if (ws_size >= need) {
        unsigned short* Xb = (unsigned short*)d_ws;
        unsigned short* Wt = Xb + xb_elems;
        hipFuncSetAttribute((const void*)gemm_8ph,
                            hipFuncAttributeMaxDynamicSharedMemorySize, 131072);
        cvt_x<<<dim3(MDIM * KDIM / (256 * 8)), dim3(256), 0, stream>>>(X, Xb);
        bin_w<<<dim3((KDIM / 64) * (NDIM / 64)), dim3(256), 0, stream>>>(W, Wt);
        gemm_8ph<<<dim3((MDIM / 256) * (NDIM / 256)), dim3(512), 131072, stream>>>(Xb, Wt, O);
    } else {
        binlin_fused<<<dim3((MDIM / 128) * (NDIM / 128)), dim3(256), 0, stream>>>(X, W, O);
    }
}

// Round 4
// 84.115 us; speedup vs baseline: 1.7923x; 1.0025x over previous
//
#include <hip/hip_runtime.h>

// BinaryLinear three-kernel:
//   cvt_x : X f32 -> bf16 (RNE)
//   bin_w : W f32 (KxN) -> binarized bf16 {0,1}, transposed to NxK
//   gemm_8ph : 256x256 tile, BK=64, 8 waves, double-buffered 128KB LDS,
//              two-barrier phases (read-before-barrier), counted vmcnt,
//              XOR-swizzled LDS, setprio (T1..T5, m201 template).
// Fallback: round-1 fused kernel if ws too small.

#define MDIM 8192
#define NDIM 2048
#define KDIM 2048
#define NT   (KDIM / 64)          // 32 K-tiles

typedef __attribute__((ext_vector_type(8))) short short8;
typedef __attribute__((ext_vector_type(4))) float float4v;
typedef __attribute__((ext_vector_type(4))) float f32x4;
typedef __attribute__((ext_vector_type(4))) unsigned short ushort4v;
typedef __attribute__((ext_vector_type(8))) unsigned short ushort8v;

__device__ __forceinline__ unsigned short f2bf(float f) {
    union { float f; unsigned u; } v; v.f = f;
    unsigned r = v.u + 0x7FFFu + ((v.u >> 16) & 1u);
    return (unsigned short)(r >> 16);
}

__device__ __forceinline__ void gload_lds16(void* l, const void* g) {
    __builtin_amdgcn_global_load_lds(
        (const __attribute__((address_space(1))) unsigned int*)g,
        (__attribute__((address_space(3))) unsigned int*)l,
        16, 0, 0);
}

#define FENCE asm volatile("" ::: "memory")
#define BAR do { FENCE; __builtin_amdgcn_s_barrier(); FENCE; } while (0)

// ---------------- pass 1a: X -> bf16 ----------------
__global__ __launch_bounds__(256) void cvt_x(const float* __restrict__ X,
                                             unsigned short* __restrict__ Xb) {
    size_t i = ((size_t)blockIdx.x * 256 + threadIdx.x) * 8;
    float4v a = *reinterpret_cast<const float4v*>(X + i);
    float4v b = *reinterpret_cast<const float4v*>(X + i + 4);
    ushort8v o;
    o[0] = f2bf(a[0]); o[1] = f2bf(a[1]); o[2] = f2bf(a[2]); o[3] = f2bf(a[3]);
    o[4] = f2bf(b[0]); o[5] = f2bf(b[1]); o[6] = f2bf(b[2]); o[7] = f2bf(b[3]);
    *reinterpret_cast<ushort8v*>(Xb + i) = o;
}

// ---------------- pass 1b: binarize + transpose W ----------------
__global__ __launch_bounds__(256) void bin_w(const float* __restrict__ W,
                                             unsigned short* __restrict__ Wt) {
    __shared__ __align__(16) unsigned short T[64][72];
    const int t = threadIdx.x;
    const int k0 = (blockIdx.x >> 5) * 64;
    const int n0 = (blockIdx.x & 31) * 64;
    const int kr = t >> 4;
    const int nc = (t & 15) * 4;
#pragma unroll
    for (int rr = 0; rr < 4; ++rr) {
        int k = k0 + rr * 16 + kr;
        float4v w4 = *reinterpret_cast<const float4v*>(W + (size_t)k * NDIM + n0 + nc);
#pragma unroll
        for (int c = 0; c < 4; ++c)
            T[nc + c][rr * 16 + kr] = (w4[c] > 0.0f) ? (unsigned short)0x3F80u
                                                     : (unsigned short)0u;
    }
    __syncthreads();
    const int nl = t >> 2, ch = t & 3;
    ushort8v v0 = *reinterpret_cast<const ushort8v*>(&T[nl][ch * 16]);
    ushort8v v1 = *reinterpret_cast<const ushort8v*>(&T[nl][ch * 16 + 8]);
    unsigned short* dst = Wt + (size_t)(n0 + nl) * KDIM + k0 + ch * 16;
    *reinterpret_cast<ushort8v*>(dst) = v0;
    *reinterpret_cast<ushort8v*>(dst + 8) = v1;
}

// ---------------- pass 2: 256x256 deep-pipelined bf16 GEMM ----------------
// LDS per buffer (64 KB): A tile [256 rows][64 k] at +0, B at +32768.
// Row stride 128 B; 16B slot s of row r holds global slot s^(r&7) (XOR
// swizzle via pre-swizzled global source). Chunk c (8 KB) = 64 rows.
// Stage order for tile t+1 during tile t: ph0 B0,B2 | ph1 B1,B3 |
// ph2 A0,A2 | ph3 A1,A3. Phase skeleton (template): {ds_read(this phase);
// stage; [vmcnt]; barrier; setprio1; 16 MFMA; setprio0; barrier}.
// vmcnt(2) at ph0 (-> cur A1,A3 resident for ph1 reads) and at ph3
// (-> next B*,A0,A2 resident for next ph0 reads).
__global__ __launch_bounds__(512, 1) void gemm_8ph(const unsigned short* __restrict__ A,
                                                   const unsigned short* __restrict__ Bt,
                                                   float* __restrict__ O) {
    extern __shared__ char lds[];
    const int tid  = threadIdx.x;
    const int lane = tid & 63;
    const int w    = tid >> 6;       // 0..7
    const int wr   = w >> 2;         // 0..1
    const int wc   = w & 3;          // 0..3

    int id  = blockIdx.x;            // 256 blocks, 256 % 8 == 0 -> bijective
    int swz = (id & 7) * 32 + (id >> 3);
    const int bm = swz >> 3;         // 0..31
    const int bn = swz & 7;          // 0..7

    // staging source: lane-row = tid>>3, pre-swizzled col slot (l7 ^ l3)
    const int l3 = lane >> 3, l7 = lane & 7;
    const int srcOff = (w * 8 + l3) * (KDIM * 2) + ((l7 ^ l3) << 4);
    const char* gA = (const char*)A + (size_t)(bm * 256) * (KDIM * 2) + srcOff;
    const char* gB = (const char*)Bt + (size_t)(bn * 256) * (KDIM * 2) + srcOff;

    // fragment read constants (swizzled)
    const int fr = lane & 15, fg = lane >> 4;
    const int se0 = ((fg)     ^ (fr & 7)) << 4;
    const int se1 = ((4 + fg) ^ (fr & 7)) << 4;
    const int aRd = wr * 16384 + fr * 128;
    const int bRd = 32768 + wc * 8192 + fr * 128;

    f32x4 acc[8][4];
#pragma unroll
    for (int i = 0; i < 8; ++i)
#pragma unroll
        for (int j = 0; j < 4; ++j) {
            acc[i][j][0] = 0.f; acc[i][j][1] = 0.f;
            acc[i][j][2] = 0.f; acc[i][j][3] = 0.f;
        }

    // prologue: stage tile 0 (steady order), drain, barrier
    gload_lds16(lds + 32768 + 0 * 8192 + w * 1024, gB + 0 * 262144);
    gload_lds16(lds + 32768 + 2 * 8192 + w * 1024, gB + 2 * 262144);
    gload_lds16(lds + 32768 + 1 * 8192 + w * 1024, gB + 1 * 262144);
    gload_lds16(lds + 32768 + 3 * 8192 + w * 1024, gB + 3 * 262144);
    gload_lds16(lds + 0 * 8192 + w * 1024, gA + 0 * 262144);
    gload_lds16(lds + 2 * 8192 + w * 1024, gA + 2 * 262144);
    gload_lds16(lds + 1 * 8192 + w * 1024, gA + 1 * 262144);
    gload_lds16(lds + 3 * 8192 + w * 1024, gA + 3 * 262144);
    asm volatile("s_waitcnt vmcnt(0)" ::: "memory");
    BAR;

    short8 af[4], bfr[4];

    for (int t = 0; t < NT; ++t) {
        const int cur = (t & 1) << 16;
        const int nxt = ((t + 1) & 1) << 16;
        const bool more = (t + 1 < NT);
        const char* gAs = gA + (size_t)(t + 1) * 128;
        const char* gBs = gB + (size_t)(t + 1) * 128;

        // ---------- phase 0: mi 0-3, kk0 ----------
#pragma unroll
        for (int j = 0; j < 4; ++j)
            af[j] = *reinterpret_cast<const short8*>(lds + cur + aRd + j * 2048 + se0);
#pragma unroll
        for (int n = 0; n < 4; ++n)
            bfr[n] = *reinterpret_cast<const short8*>(lds + cur + bRd + n * 2048 + se0);
        if (more) {
            gload_lds16(lds + nxt + 32768 + 0 * 8192 + w * 1024, gBs + 0 * 262144);
            gload_lds16(lds + nxt + 32768 + 2 * 8192 + w * 1024, gBs + 2 * 262144);
        }
        if (more) asm volatile("s_waitcnt vmcnt(2)" ::: "memory");
        else      asm volatile("s_waitcnt vmcnt(0)" ::: "memory");
        BAR;
        __builtin_amdgcn_s_setprio(1);
#pragma unroll
        for (int mi = 0; mi < 4; ++mi)
#pragma unroll
            for (int ni = 0; ni < 4; ++ni)
                acc[mi][ni] = __builtin_amdgcn_mfma_f32_16x16x32_bf16(
                    af[mi], bfr[ni], acc[mi][ni], 0, 0, 0);
        __builtin_amdgcn_s_setprio(0);
        BAR;

        // ---------- phase 1: mi 4-7, kk0 ----------
#pragma unroll
        for (int j = 0; j < 4; ++j)
            af[j] = *reinterpret_cast<const short8*>(lds + cur + aRd + (4 + j) * 2048 + se0);
        if (more) {
            gload_lds16(lds + nxt + 32768 + 1 * 8192 + w * 1024, gBs + 1 * 262144);
            gload_lds16(lds + nxt + 32768 + 3 * 8192 + w * 1024, gBs + 3 * 262144);
        }
        BAR;
        __builtin_amdgcn_s_setprio(1);
#pragma unroll
        for (int mi = 0; mi < 4; ++mi)
#pragma unroll
            for (int ni = 0; ni < 4; ++ni)
                acc[4 + mi][ni] = __builtin_amdgcn_mfma_f32_16x16x32_bf16(
                    af[mi], bfr[ni], acc[4 + mi][ni], 0, 0, 0);
        __builtin_amdgcn_s_setprio(0);
        BAR;

        // ---------- phase 2: mi 0-3, kk1 ----------
#pragma unroll
        for (int j = 0; j < 4; ++j)
            af[j] = *reinterpret_cast<const short8*>(lds + cur + aRd + j * 2048 + se1);
#pragma unroll
        for (int n = 0; n < 4; ++n)
            bfr[n] = *reinterpret_cast<const short8*>(lds + cur + bRd + n * 2048 + se1);
        if (more) {
            gload_lds16(lds + nxt + 0 * 8192 + w * 1024, gAs + 0 * 262144);
            gload_lds16(lds + nxt + 2 * 8192 + w * 1024, gAs + 2 * 262144);
        }
        BAR;
        __builtin_amdgcn_s_setprio(1);
#pragma unroll
        for (int mi = 0; mi < 4; ++mi)
#pragma unroll
            for (int ni = 0; ni < 4; ++ni)
                acc[mi][ni] = __builtin_amdgcn_mfma_f32_16x16x32_bf16(
                    af[mi], bfr[ni], acc[mi][ni], 0, 0, 0);
        __builtin_amdgcn_s_setprio(0);
        BAR;

        // ---------- phase 3: mi 4-7, kk1 ----------
#pragma unroll
        for (int j = 0; j < 4; ++j)
            af[j] = *reinterpret_cast<const short8*>(lds + cur + aRd + (4 + j) * 2048 + se1);
        if (more) {
            gload_lds16(lds + nxt + 1 * 8192 + w * 1024, gAs + 1 * 262144);
            gload_lds16(lds + nxt + 3 * 8192 + w * 1024, gAs + 3 * 262144);
            asm volatile("s_waitcnt vmcnt(2)" ::: "memory");
        }
        BAR;
        __builtin_amdgcn_s_setprio(1);
#pragma unroll
        for (int mi = 0; mi < 4; ++mi)
#pragma unroll
            for (int ni = 0; ni < 4; ++ni)
                acc[4 + mi][ni] = __builtin_amdgcn_mfma_f32_16x16x32_bf16(
                    af[mi], bfr[ni], acc[4 + mi][ni], 0, 0, 0);
        __builtin_amdgcn_s_setprio(0);
        BAR;
    }

    // ---- epilogue: C/D layout col = lane&15, row = 4*(lane>>4) + reg ----
    const int orow0 = bm * 256 + wr * 128 + fg * 4;
    const int ocol0 = bn * 256 + wc * 64 + fr;
#pragma unroll
    for (int mi = 0; mi < 8; ++mi)
#pragma unroll
        for (int r = 0; r < 4; ++r) {
            float* op = O + (size_t)(orow0 + mi * 16 + r) * NDIM + ocol0;
#pragma unroll
            for (int ni = 0; ni < 4; ++ni)
                op[ni * 16] = acc[mi][ni][r];
        }
}

// ---------------- fallback: round-1 fused kernel ----------------
__global__ __launch_bounds__(256, 2) void binlin_fused(
        const float* __restrict__ X, const float* __restrict__ W,
        float* __restrict__ O) {
    const int tid = threadIdx.x;
    const int lane = tid & 63;
    const int wave = tid >> 6;
    const int wr = wave >> 1, wc = wave & 1;
    const int NWG = (MDIM / 128) * (NDIM / 128);
    int id = blockIdx.x;
    int swz = (id & 7) * (NWG >> 3) + (id >> 3);
    const int bm = swz >> 4, bn = swz & 15;

    __shared__ __align__(16) unsigned short As[128][40];
    __shared__ __align__(16) unsigned short Bs[128][40];

    const int rA = tid >> 3, kA = (tid & 7) * 4;
    const float* aPtr = X + (size_t)(bm * 128 + rA) * KDIM + kA;
    const int nB = (tid & 31) * 4, kB = (tid >> 5) * 4;
    const float* bPtr = W + (size_t)kB * NDIM + (size_t)bn * 128 + nB;

    float4v aReg[4], bReg[4];
#pragma unroll
    for (int p = 0; p < 4; ++p)
        aReg[p] = *reinterpret_cast<const float4v*>(aPtr + (size_t)(32 * p) * KDIM);
#pragma unroll
    for (int dk = 0; dk < 4; ++dk)
        bReg[dk] = *reinterpret_cast<const float4v*>(bPtr + (size_t)dk * NDIM);

    f32x4 acc[4][4];
#pragma unroll
    for (int i = 0; i < 4; ++i)
#pragma unroll
        for (int j = 0; j < 4; ++j) {
            acc[i][j][0] = 0.f; acc[i][j][1] = 0.f; acc[i][j][2] = 0.f; acc[i][j][3] = 0.f;
        }

    const int r16 = lane & 15, g8 = (lane >> 4) * 8;
    for (int kt = 0; kt < KDIM; kt += 32) {
#pragma unroll
        for (int p = 0; p < 4; ++p) {
            ushort4v v;
            v[0] = f2bf(aReg[p][0]); v[1] = f2bf(aReg[p][1]);
            v[2] = f2bf(aReg[p][2]); v[3] = f2bf(aReg[p][3]);
            *reinterpret_cast<ushort4v*>(&As[rA + 32 * p][kA]) = v;
        }
        unsigned short bb[4][4];
#pragma unroll
        for (int dk = 0; dk < 4; ++dk)
#pragma unroll
            for (int dn = 0; dn < 4; ++dn)
                bb[dn][dk] = (bReg[dk][dn] > 0.0f) ? (unsigned short)0x3F80u
                                                   : (unsigned short)0u;
#pragma unroll
        for (int dn = 0; dn < 4; ++dn) {
            ushort4v v;
            v[0] = bb[dn][0]; v[1] = bb[dn][1]; v[2] = bb[dn][2]; v[3] = bb[dn][3];
            *reinterpret_cast<ushort4v*>(&Bs[nB + dn][kB]) = v;
        }
        __syncthreads();
        if (kt + 32 < KDIM) {
#pragma unroll
            for (int p = 0; p < 4; ++p)
                aReg[p] = *reinterpret_cast<const float4v*>(
                    aPtr + (size_t)(32 * p) * KDIM + (kt + 32));
#pragma unroll
            for (int dk = 0; dk < 4; ++dk)
                bReg[dk] = *reinterpret_cast<const float4v*>(
                    bPtr + (size_t)(kt + 32 + dk) * NDIM);
        }
        short8 af[4], bf[4];
#pragma unroll
        for (int mi = 0; mi < 4; ++mi)
            af[mi] = *reinterpret_cast<const short8*>(&As[wr * 64 + mi * 16 + r16][g8]);
#pragma unroll
        for (int ni = 0; ni < 4; ++ni)
            bf[ni] = *reinterpret_cast<const short8*>(&Bs[wc * 64 + ni * 16 + r16][g8]);
#pragma unroll
        for (int mi = 0; mi < 4; ++mi)
#pragma unroll
            for (int ni = 0; ni < 4; ++ni)
                acc[mi][ni] = __builtin_amdgcn_mfma_f32_16x16x32_bf16(
                    af[mi], bf[ni], acc[mi][ni], 0, 0, 0);
        __syncthreads();
    }

    const int orow0 = bm * 128 + wr * 64 + (lane >> 4) * 4;
    const int ocol0 = bn * 128 + wc * 64 + r16;
#pragma unroll
    for (int mi = 0; mi < 4; ++mi)
#pragma unroll
        for (int ni = 0; ni < 4; ++ni)
#pragma unroll
            for (int r = 0; r < 4; ++r)
                O[(size_t)(orow0 + mi * 16 + r) * NDIM + ocol0 + ni * 16] =
                    acc[mi][ni][r];
}

extern "C" void kernel_launch(void* const* d_in, const int* in_sizes, int n_in,
                              void* d_out, int out_size, void* d_ws, size_t ws_size,
                              hipStream_t stream) {
    const float* X = (const float*)d_in[0];
    const float* W = (const float*)d_in[1];
    float* O = (float*)d_out;
    (void)in_sizes; (void)n_in; (void)out_size;

    const size_t xb_elems = (size_t)MDIM * KDIM;
    const size_t wt_elems = (size_t)NDIM * KDIM;
    const size_t need = (xb_elems + wt_elems) * sizeof(unsigned short);

    if (ws_size >= need) {
        unsigned short* Xb = (unsigned short*)d_ws;
        unsigned short* Wt = Xb + xb_elems;
        hipFuncSetAttribute((const void*)gemm_8ph,
                            hipFuncAttributeMaxDynamicSharedMemorySize, 131072);
        cvt_x<<<dim3(MDIM * KDIM / (256 * 8)), dim3(256), 0, stream>>>(X, Xb);
        bin_w<<<dim3((KDIM / 64) * (NDIM / 64)), dim3(256), 0, stream>>>(W, Wt);
        gemm_8ph<<<dim3((MDIM / 256) * (NDIM / 256)), dim3(512), 131072, stream>>>(Xb, Wt, O);
    } else {
        binlin_fused<<<dim3((MDIM / 128) * (NDIM / 128)), dim3(256), 0, stream>>>(X, W, O);
    }
}